// Round 1
// baseline (7889.802 us; speedup 1.0000x reference)
//
#include <hip/hip_runtime.h>
#include <math.h>

#define MSLOTS 8
#define DMEM   1024
#define NGATES 2048
#define NB     128
#define NT     32

// ---------------------------------------------------------------------------
// Generic fp32 GEMM: C = act(A @ W + bias)
// A: (M x K) row stride lda ; W: (K x N) row-major ; C row stride ldc.
// Batched over blockIdx.z via element strides zsA/zsW/zsC.
// Tiles: 64x64, BK=16, 256 threads, 4x4 per thread. M,N multiples of 64,
// K multiple of 16 (all shapes here satisfy this).
// ---------------------------------------------------------------------------
__global__ __launch_bounds__(256)
void gemm_f32_kern(const float* __restrict__ A, int lda, long zsA,
                   const float* __restrict__ W, long zsW,
                   const float* __restrict__ bias,
                   float* __restrict__ C, int ldc, long zsC,
                   int K, int N, int act)
{
    __shared__ float As[16][68];
    __shared__ float Bs[16][68];

    A += (long)blockIdx.z * zsA;
    W += (long)blockIdx.z * zsW;
    C += (long)blockIdx.z * zsC;

    const int tid = threadIdx.x;
    const int tr  = tid >> 4;          // 0..15
    const int tc  = tid & 15;          // 0..15
    const int row0 = blockIdx.y * 64;
    const int col0 = blockIdx.x * 64;

    // staging indices
    const int ar = tid >> 2;           // 0..63  (tile row)
    const int ak = (tid & 3) << 2;     // 0,4,8,12
    const int wk = tid >> 4;           // 0..15  (tile k)
    const int wc = (tid & 15) << 2;    // 0..60

    float acc[4][4] = {};

    for (int k0 = 0; k0 < K; k0 += 16) {
        float4 a = *(const float4*)(A + (long)(row0 + ar) * lda + k0 + ak);
        float4 w = *(const float4*)(W + (long)(k0 + wk) * N + col0 + wc);
        __syncthreads();
        As[ak + 0][ar] = a.x;
        As[ak + 1][ar] = a.y;
        As[ak + 2][ar] = a.z;
        As[ak + 3][ar] = a.w;
        *(float4*)&Bs[wk][wc] = w;
        __syncthreads();
#pragma unroll
        for (int kk = 0; kk < 16; ++kk) {
            float4 av = *(const float4*)&As[kk][tr << 2];
            float4 bv = *(const float4*)&Bs[kk][tc << 2];
            acc[0][0] += av.x * bv.x; acc[0][1] += av.x * bv.y;
            acc[0][2] += av.x * bv.z; acc[0][3] += av.x * bv.w;
            acc[1][0] += av.y * bv.x; acc[1][1] += av.y * bv.y;
            acc[1][2] += av.y * bv.z; acc[1][3] += av.y * bv.w;
            acc[2][0] += av.z * bv.x; acc[2][1] += av.z * bv.y;
            acc[2][2] += av.z * bv.z; acc[2][3] += av.z * bv.w;
            acc[3][0] += av.w * bv.x; acc[3][1] += av.w * bv.y;
            acc[3][2] += av.w * bv.z; acc[3][3] += av.w * bv.w;
        }
    }

    float4 bvv = make_float4(0.f, 0.f, 0.f, 0.f);
    if (bias) bvv = *(const float4*)&bias[col0 + (tc << 2)];
#pragma unroll
    for (int i = 0; i < 4; ++i) {
        int row = row0 + (tr << 2) + i;
        float4 o = make_float4(acc[i][0] + bvv.x, acc[i][1] + bvv.y,
                               acc[i][2] + bvv.z, acc[i][3] + bvv.w);
        if (act == 1) {
            o.x = fmaxf(o.x, 0.f); o.y = fmaxf(o.y, 0.f);
            o.z = fmaxf(o.z, 0.f); o.w = fmaxf(o.w, 0.f);
        }
        *(float4*)(C + (long)row * ldc + col0 + (tc << 2)) = o;
    }
}

// ---------------------------------------------------------------------------
// block reduction over 256 threads (4 waves) of (sum, sumsq)
// ---------------------------------------------------------------------------
__device__ inline void block_reduce2(float& s1, float& s2)
{
    __shared__ float red[2][4];
#pragma unroll
    for (int off = 32; off > 0; off >>= 1) {
        s1 += __shfl_down(s1, off, 64);
        s2 += __shfl_down(s2, off, 64);
    }
    int tid = threadIdx.x;
    if ((tid & 63) == 0) { red[0][tid >> 6] = s1; red[1][tid >> 6] = s2; }
    __syncthreads();
    s1 = red[0][0] + red[0][1] + red[0][2] + red[0][3];
    s2 = red[1][0] + red[1][1] + red[1][2] + red[1][3];
}

__device__ inline float sigmoidf_(float x) { return 1.f / (1.f + __expf(-x)); }

// ---------------------------------------------------------------------------
// LN1: m1 = LN(mem + v_t)*g+b   and  tm = tanh(mem)
// one block per (b,s) row; 256 threads, float4 each
// ---------------------------------------------------------------------------
__global__ __launch_bounds__(256)
void ln1_kern(const float* __restrict__ memprev, const float* __restrict__ v, int t,
              const float* __restrict__ g, const float* __restrict__ bta,
              float* __restrict__ m1, float* __restrict__ tm)
{
    const int row = blockIdx.x;          // b*8+s
    const int b   = row >> 3;
    const int d   = threadIdx.x << 2;

    const float* mrow = memprev + (long)row * DMEM;
    const float* vrow = v + ((long)b * NT + t) * DMEM;

    float4 mv = *(const float4*)(mrow + d);
    float4 vv = *(const float4*)(vrow + d);
    float4 x  = make_float4(mv.x + vv.x, mv.y + vv.y, mv.z + vv.z, mv.w + vv.w);

    float4 tmv = make_float4(tanhf(mv.x), tanhf(mv.y), tanhf(mv.z), tanhf(mv.w));
    *(float4*)(tm + (long)row * DMEM + d) = tmv;

    float s1 = x.x + x.y + x.z + x.w;
    float s2 = x.x * x.x + x.y * x.y + x.z * x.z + x.w * x.w;
    block_reduce2(s1, s2);
    float mean = s1 * (1.f / 1024.f);
    float var  = s2 * (1.f / 1024.f) - mean * mean;
    float inv  = 1.f / sqrtf(var + 1e-5f);

    float4 gg = *(const float4*)&g[d];
    float4 bb = *(const float4*)&bta[d];
    float4 o = make_float4((x.x - mean) * inv * gg.x + bb.x,
                           (x.y - mean) * inv * gg.y + bb.y,
                           (x.z - mean) * inv * gg.z + bb.z,
                           (x.w - mean) * inv * gg.w + bb.w);
    *(float4*)(m1 + (long)row * DMEM + d) = o;
}

// ---------------------------------------------------------------------------
// LN2: t2 = tanh(LN(m1 + h2)*g+b)
// ---------------------------------------------------------------------------
__global__ __launch_bounds__(256)
void ln2_kern(const float* __restrict__ m1, const float* __restrict__ h2,
              const float* __restrict__ g, const float* __restrict__ bta,
              float* __restrict__ t2)
{
    const int row = blockIdx.x;
    const int d   = threadIdx.x << 2;

    float4 a = *(const float4*)(m1 + (long)row * DMEM + d);
    float4 h = *(const float4*)(h2 + (long)row * DMEM + d);
    float4 x = make_float4(a.x + h.x, a.y + h.y, a.z + h.z, a.w + h.w);

    float s1 = x.x + x.y + x.z + x.w;
    float s2 = x.x * x.x + x.y * x.y + x.z * x.z + x.w * x.w;
    block_reduce2(s1, s2);
    float mean = s1 * (1.f / 1024.f);
    float var  = s2 * (1.f / 1024.f) - mean * mean;
    float inv  = 1.f / sqrtf(var + 1e-5f);

    float4 gg = *(const float4*)&g[d];
    float4 bb = *(const float4*)&bta[d];
    float4 o = make_float4(tanhf((x.x - mean) * inv * gg.x + bb.x),
                           tanhf((x.y - mean) * inv * gg.y + bb.y),
                           tanhf((x.z - mean) * inv * gg.z + bb.z),
                           tanhf((x.w - mean) * inv * gg.w + bb.w));
    *(float4*)(t2 + (long)row * DMEM + d) = o;
}

// ---------------------------------------------------------------------------
// gates + state update:  out = sigmoid(gm+gi+ib)*t2 + sigmoid(gm'+gi'+fb)*mem
// ---------------------------------------------------------------------------
__global__ __launch_bounds__(256)
void gate_kern(const float* __restrict__ gm, const float* __restrict__ gi, int t,
               const float* __restrict__ t2, const float* __restrict__ memprev,
               const float* __restrict__ fbp, const float* __restrict__ ibp,
               float* __restrict__ outp)
{
    const int row = blockIdx.x;          // b*8+s
    const int b   = row >> 3;
    const int d   = threadIdx.x << 2;
    const float ib = *ibp;
    const float fb = *fbp;

    const float* gmrow = gm + (long)row * NGATES;
    const float* girow = gi + ((long)b * NT + t) * NGATES;

    float4 g0 = *(const float4*)(gmrow + d);
    float4 gi0 = *(const float4*)(girow + d);
    float4 g1 = *(const float4*)(gmrow + DMEM + d);
    float4 gi1 = *(const float4*)(girow + DMEM + d);
    float4 tv = *(const float4*)(t2 + (long)row * DMEM + d);
    float4 mv = *(const float4*)(memprev + (long)row * DMEM + d);

    float4 o;
    o.x = sigmoidf_(g0.x + gi0.x + ib) * tv.x + sigmoidf_(g1.x + gi1.x + fb) * mv.x;
    o.y = sigmoidf_(g0.y + gi0.y + ib) * tv.y + sigmoidf_(g1.y + gi1.y + fb) * mv.y;
    o.z = sigmoidf_(g0.z + gi0.z + ib) * tv.z + sigmoidf_(g1.z + gi1.z + fb) * mv.z;
    o.w = sigmoidf_(g0.w + gi0.w + ib) * tv.w + sigmoidf_(g1.w + gi1.w + fb) * mv.w;
    *(float4*)(outp + (long)row * DMEM + d) = o;
}

// ---------------------------------------------------------------------------
// ga = relu(rep_w * inp), elementwise over (B*T, 1024)
// ---------------------------------------------------------------------------
__global__ __launch_bounds__(256)
void ga_kern(const float* __restrict__ inp, const float* __restrict__ rep,
             float* __restrict__ ga)
{
    long i4 = ((long)blockIdx.x * 256 + threadIdx.x) << 2;
    float4 x = *(const float4*)&inp[i4];
    float4 r = *(const float4*)&rep[i4 & (DMEM - 1)];
    float4 o = make_float4(fmaxf(r.x * x.x, 0.f), fmaxf(r.y * x.y, 0.f),
                           fmaxf(r.z * x.z, 0.f), fmaxf(r.w * x.w, 0.f));
    *(float4*)&ga[i4] = o;
}

// ---------------------------------------------------------------------------
extern "C" void kernel_launch(void* const* d_in, const int* in_sizes, int n_in,
                              void* d_out, int out_size, void* d_ws, size_t ws_size,
                              hipStream_t stream)
{
    const float* x    = (const float*)d_in[0];
    const float* mem0 = (const float*)d_in[1];
    const float* Wi   = (const float*)d_in[2];
    const float* bi   = (const float*)d_in[3];
    // d_in[4..7] = Wq,bq,Wk,bk : dead code (softmax over singleton axis == 1)
    const float* Wv   = (const float*)d_in[8];
    const float* bv   = (const float*)d_in[9];
    const float* Wm   = (const float*)d_in[10];
    const float* bm   = (const float*)d_in[11];
    const float* ln1g = (const float*)d_in[12];
    const float* ln1b = (const float*)d_in[13];
    const float* ln2g = (const float*)d_in[14];
    const float* ln2b = (const float*)d_in[15];
    const float* repw = (const float*)d_in[16];
    const float* Wg   = (const float*)d_in[17];
    const float* bg   = (const float*)d_in[18];
    const float* Wmg  = (const float*)d_in[19];
    const float* fbp  = (const float*)d_in[20];
    const float* ibp  = (const float*)d_in[21];

    float* out = (float*)d_out;
    float* ws  = (float*)d_ws;

    // phase-A buffers
    float* inp = ws;                  // 4M floats (B*T*1024)
    float* ga  = ws + 4194304;        // 4M
    float* v   = ws + 8388608;        // 4M
    float* gi  = ws + 12582912;       // 8M (B*T*2048)
    // per-step buffers overlay inp/ga (dead after phase A)
    float* m1  = ws;                  // 1M
    float* h1  = ws + 1048576;        // 1M
    float* h2  = ws + 2097152;        // 1M
    float* t2  = ws + 3145728;        // 1M
    float* tm  = ws + 4194304;        // 1M
    float* gm  = ws + 5242880;        // 2M (B*S*2048)
    // total ws use: 20,971,520 floats = 80 MB

    dim3 blk(256);

    // ---- phase A: all time steps at once ----
    // inp = x @ Wi + bi      (4096 x 1024 x 1024)
    gemm_f32_kern<<<dim3(16, 64, 1), blk, 0, stream>>>(x, 1024, 0, Wi, 0, bi,
                                                       inp, 1024, 0, 1024, 1024, 0);
    // ga = relu(rep_w * inp)
    ga_kern<<<4096, blk, 0, stream>>>(inp, repw, ga);
    // v = inp @ Wv + bv
    gemm_f32_kern<<<dim3(16, 64, 1), blk, 0, stream>>>(inp, 1024, 0, Wv, 0, bv,
                                                       v, 1024, 0, 1024, 1024, 0);
    // gi = ga @ Wg + bg      (4096 x 2048 x 1024)
    gemm_f32_kern<<<dim3(32, 64, 1), blk, 0, stream>>>(ga, 1024, 0, Wg, 0, bg,
                                                       gi, 2048, 0, 1024, 2048, 0);

    // ---- recurrent scan; state lives in d_out (outs[t] == new_mem_t) ----
    const long stepN = (long)NB * MSLOTS * DMEM;   // 1,048,576
    for (int t = 0; t < NT; ++t) {
        const float* memprev = (t == 0) ? mem0 : out + (long)(t - 1) * stepN;

        ln1_kern<<<1024, blk, 0, stream>>>(memprev, v, t, ln1g, ln1b, m1, tm);

        // h1 = relu(m1 @ Wm + bm)   (1024 x 1024 x 1024)
        gemm_f32_kern<<<dim3(16, 16, 1), blk, 0, stream>>>(m1, 1024, 0, Wm, 0, bm,
                                                           h1, 1024, 0, 1024, 1024, 1);
        // h2 = relu(h1 @ Wm + bm)
        gemm_f32_kern<<<dim3(16, 16, 1), blk, 0, stream>>>(h1, 1024, 0, Wm, 0, bm,
                                                           h2, 1024, 0, 1024, 1024, 1);

        ln2_kern<<<1024, blk, 0, stream>>>(m1, h2, ln2g, ln2b, t2);

        // gm[b,s,:] = tanh(mem)[b,s,:] @ Wmg[s]   (z=slot, 128 x 2048 x 1024)
        gemm_f32_kern<<<dim3(32, 2, 8), blk, 0, stream>>>(tm, 8192, 1024,
                                                          Wmg, 2097152, nullptr,
                                                          gm, 16384, 2048, 1024, 2048, 0);

        gate_kern<<<1024, blk, 0, stream>>>(gm, gi, t, t2, memprev, fbp, ibp,
                                            out + (long)t * stepN);
    }

    // final_mem = outs[31]
    hipMemcpyAsync(out + 32L * stepN, out + 31L * stepN, stepN * sizeof(float),
                   hipMemcpyDeviceToDevice, stream);
}

// Round 3
// 5433.648 us; speedup vs baseline: 1.4520x; 1.4520x over previous
//
#include <hip/hip_runtime.h>
#include <math.h>

#define DMEM   1024
#define NGATES 2048
#define NB     128
#define NT     32

__device__ inline float sigm(float x) { return 1.f / (1.f + __expf(-x)); }

// ---------------------------------------------------------------------------
// gemm128: fp32, C = A@W + bias. 128x128 tile, BK=16, 256 thr, 8x8/thread.
// A (MxK) row-major, W (KxN) row-major. M,N mult of 128, K mult of 16.
// Per-thread tile split as rows {tr..tr+3, 64+tr..} x cols {tc.., 64+tc..}
// so LDS fragment reads are stride-16B (2-way bank alias = free).
// ---------------------------------------------------------------------------
__global__ __launch_bounds__(256)
void gemm128(const float* __restrict__ A, int lda,
             const float* __restrict__ W, int N,
             const float* __restrict__ bias,
             float* __restrict__ C, int K)
{
    __shared__ float As[16][132];
    __shared__ float Bs[16][132];
    const int tid  = threadIdx.x;
    const int tr   = (tid >> 4) << 2;          // 0..60
    const int tc   = (tid & 15) << 2;          // 0..60
    const int row0 = blockIdx.y * 128, col0 = blockIdx.x * 128;
    const int arow = tid >> 1, ah = (tid & 1) * 8;
    const int brow = tid >> 4, bcol = (tid & 15) * 8;

    float acc[8][8] = {};

    for (int k0 = 0; k0 < K; k0 += 16) {
        const float* ap = A + (long)(row0 + arow) * lda + k0 + ah;
        float4 a0 = *(const float4*)ap;
        float4 a1 = *(const float4*)(ap + 4);
        const float* bp = W + (long)(k0 + brow) * N + col0 + bcol;
        float4 b0 = *(const float4*)bp;
        float4 b1 = *(const float4*)(bp + 4);
        __syncthreads();
        As[ah + 0][arow] = a0.x; As[ah + 1][arow] = a0.y;
        As[ah + 2][arow] = a0.z; As[ah + 3][arow] = a0.w;
        As[ah + 4][arow] = a1.x; As[ah + 5][arow] = a1.y;
        As[ah + 6][arow] = a1.z; As[ah + 7][arow] = a1.w;
        *(float4*)&Bs[brow][bcol]     = b0;
        *(float4*)&Bs[brow][bcol + 4] = b1;
        __syncthreads();
#pragma unroll
        for (int kk = 0; kk < 16; ++kk) {
            float a[8], b[8];
            *(float4*)&a[0] = *(const float4*)&As[kk][tr];
            *(float4*)&a[4] = *(const float4*)&As[kk][64 + tr];
            *(float4*)&b[0] = *(const float4*)&Bs[kk][tc];
            *(float4*)&b[4] = *(const float4*)&Bs[kk][64 + tc];
#pragma unroll
            for (int i = 0; i < 8; ++i)
#pragma unroll
                for (int j = 0; j < 8; ++j)
                    acc[i][j] = fmaf(a[i], b[j], acc[i][j]);
        }
    }

#pragma unroll
    for (int jh = 0; jh < 2; ++jh) {
        int cbase = col0 + jh * 64 + tc;
        float4 bv = make_float4(0.f, 0.f, 0.f, 0.f);
        if (bias) bv = *(const float4*)&bias[cbase];
#pragma unroll
        for (int ih = 0; ih < 2; ++ih) {
#pragma unroll
            for (int i = 0; i < 4; ++i) {
                int row = row0 + ih * 64 + tr + i;
                float4 o = make_float4(acc[ih*4+i][jh*4+0] + bv.x,
                                       acc[ih*4+i][jh*4+1] + bv.y,
                                       acc[ih*4+i][jh*4+2] + bv.z,
                                       acc[ih*4+i][jh*4+3] + bv.w);
                *(float4*)(C + (long)row * N + cbase) = o;
            }
        }
    }
}

// ---------------------------------------------------------------------------
// gemm64: fp32, raw C (no bias/act). 64x64 tile, BK=32, 256 thr, 4x4/thread.
//  AMODE 0: A plain fp32 (MxK, lda)
//  AMODE 1: A[m][k] = relu(P0[m*lda+k] + P0[pstride + ...] + abias[k])
//  ZMODE 1: split-K2 (blockIdx.z = k-chunk; C += z*zsC)
//  ZMODE 2: batch   (blockIdx.z = slot; A += z*zsA, W += z*zsW, C += z*zsC)
// ---------------------------------------------------------------------------
template<int AMODE, int ZMODE>
__global__ __launch_bounds__(256)
void gemm64(const float* __restrict__ A, int lda, long zsA, long pstride,
            const float* __restrict__ abias,
            const float* __restrict__ W, int N, long zsW,
            float* __restrict__ C, int ldc, long zsC,
            int K)
{
    __shared__ float As[32][68];
    __shared__ float Bs[32][68];
    const int tid = threadIdx.x;
    const int z   = blockIdx.z;
    int kbeg = 0, kend = K;
    if (ZMODE == 1) { int kc = K >> 1; kbeg = z * kc; kend = kbeg + kc; C += (long)z * zsC; }
    if (ZMODE == 2) { A += (long)z * zsA; W += (long)z * zsW; C += (long)z * zsC; }

    const int row0 = blockIdx.y * 64, col0 = blockIdx.x * 64;
    const int tr = (tid >> 4) << 2, tc = (tid & 15) << 2;
    const int arow = tid >> 2, aseg = (tid & 3) * 8;
    const int brow = tid >> 3, bcol = (tid & 7) * 8;

    float acc[4][4] = {};

    for (int k0 = kbeg; k0 < kend; k0 += 32) {
        float4 a0, a1;
        if (AMODE == 0) {
            const float* ap = A + (long)(row0 + arow) * lda + k0 + aseg;
            a0 = *(const float4*)ap;
            a1 = *(const float4*)(ap + 4);
        } else {
            const float* p0 = A + (long)(row0 + arow) * lda + k0 + aseg;
            const float* p1 = p0 + pstride;
            float4 q0 = *(const float4*)p0, q1 = *(const float4*)(p0 + 4);
            float4 r0 = *(const float4*)p1, r1 = *(const float4*)(p1 + 4);
            float4 c0 = *(const float4*)(abias + k0 + aseg);
            float4 c1 = *(const float4*)(abias + k0 + aseg + 4);
            a0.x = fmaxf(q0.x + r0.x + c0.x, 0.f);
            a0.y = fmaxf(q0.y + r0.y + c0.y, 0.f);
            a0.z = fmaxf(q0.z + r0.z + c0.z, 0.f);
            a0.w = fmaxf(q0.w + r0.w + c0.w, 0.f);
            a1.x = fmaxf(q1.x + r1.x + c1.x, 0.f);
            a1.y = fmaxf(q1.y + r1.y + c1.y, 0.f);
            a1.z = fmaxf(q1.z + r1.z + c1.z, 0.f);
            a1.w = fmaxf(q1.w + r1.w + c1.w, 0.f);
        }
        const float* bp = W + (long)(k0 + brow) * N + col0 + bcol;
        float4 b0 = *(const float4*)bp;
        float4 b1 = *(const float4*)(bp + 4);
        __syncthreads();
        As[aseg + 0][arow] = a0.x; As[aseg + 1][arow] = a0.y;
        As[aseg + 2][arow] = a0.z; As[aseg + 3][arow] = a0.w;
        As[aseg + 4][arow] = a1.x; As[aseg + 5][arow] = a1.y;
        As[aseg + 6][arow] = a1.z; As[aseg + 7][arow] = a1.w;
        *(float4*)&Bs[brow][bcol]     = b0;
        *(float4*)&Bs[brow][bcol + 4] = b1;
        __syncthreads();
#pragma unroll
        for (int kk = 0; kk < 32; ++kk) {
            float4 av = *(const float4*)&As[kk][tr];
            float4 bv = *(const float4*)&Bs[kk][tc];
            acc[0][0] = fmaf(av.x, bv.x, acc[0][0]); acc[0][1] = fmaf(av.x, bv.y, acc[0][1]);
            acc[0][2] = fmaf(av.x, bv.z, acc[0][2]); acc[0][3] = fmaf(av.x, bv.w, acc[0][3]);
            acc[1][0] = fmaf(av.y, bv.x, acc[1][0]); acc[1][1] = fmaf(av.y, bv.y, acc[1][1]);
            acc[1][2] = fmaf(av.y, bv.z, acc[1][2]); acc[1][3] = fmaf(av.y, bv.w, acc[1][3]);
            acc[2][0] = fmaf(av.z, bv.x, acc[2][0]); acc[2][1] = fmaf(av.z, bv.y, acc[2][1]);
            acc[2][2] = fmaf(av.z, bv.z, acc[2][2]); acc[2][3] = fmaf(av.z, bv.w, acc[2][3]);
            acc[3][0] = fmaf(av.w, bv.x, acc[3][0]); acc[3][1] = fmaf(av.w, bv.y, acc[3][1]);
            acc[3][2] = fmaf(av.w, bv.z, acc[3][2]); acc[3][3] = fmaf(av.w, bv.w, acc[3][3]);
        }
    }

#pragma unroll
    for (int i = 0; i < 4; ++i) {
        int row = row0 + tr + i;
        *(float4*)(C + (long)row * ldc + col0 + tc) =
            make_float4(acc[i][0], acc[i][1], acc[i][2], acc[i][3]);
    }
}

// ---------------------------------------------------------------------------
// block reduction (256 threads) of (sum, sumsq)
// ---------------------------------------------------------------------------
__device__ inline void block_reduce2(float& s1, float& s2)
{
    __shared__ float red[2][4];
#pragma unroll
    for (int off = 32; off > 0; off >>= 1) {
        s1 += __shfl_down(s1, off, 64);
        s2 += __shfl_down(s2, off, 64);
    }
    int tid = threadIdx.x;
    if ((tid & 63) == 0) { red[0][tid >> 6] = s1; red[1][tid >> 6] = s2; }
    __syncthreads();
    s1 = red[0][0] + red[0][1] + red[0][2] + red[0][3];
    s2 = red[1][0] + red[1][1] + red[1][2] + red[1][3];
}

// ---------------------------------------------------------------------------
// ln1 (t=0): m1 = LN(mem0 + v[:,0])*g+b ; tm = tanh(mem0)
// ---------------------------------------------------------------------------
__global__ __launch_bounds__(256)
void ln1_kern(const float* __restrict__ memprev, const float* __restrict__ v,
              const float* __restrict__ g, const float* __restrict__ bb,
              float* __restrict__ m1, float* __restrict__ tm)
{
    const int row = blockIdx.x;          // b*8+s
    const int b   = row >> 3;
    const int d   = threadIdx.x << 2;

    float4 mv = *(const float4*)(memprev + (long)row * DMEM + d);
    float4 vv = *(const float4*)(v + ((long)b * NT) * DMEM + d);

    float4 tmo = make_float4(tanhf(mv.x), tanhf(mv.y), tanhf(mv.z), tanhf(mv.w));
    *(float4*)(tm + (long)row * DMEM + d) = tmo;

    float x0 = mv.x + vv.x, x1 = mv.y + vv.y, x2 = mv.z + vv.z, x3 = mv.w + vv.w;
    float s1 = x0 + x1 + x2 + x3;
    float s2 = x0 * x0 + x1 * x1 + x2 * x2 + x3 * x3;
    block_reduce2(s1, s2);
    float mean = s1 * (1.f / 1024.f);
    float var  = s2 * (1.f / 1024.f) - mean * mean;
    float inv  = 1.f / sqrtf(var + 1e-5f);

    float4 gg = *(const float4*)&g[d];
    float4 bv = *(const float4*)&bb[d];
    *(float4*)(m1 + (long)row * DMEM + d) =
        make_float4((x0 - mean) * inv * gg.x + bv.x,
                    (x1 - mean) * inv * gg.y + bv.y,
                    (x2 - mean) * inv * gg.z + bv.z,
                    (x3 - mean) * inv * gg.w + bv.w);
}

// ---------------------------------------------------------------------------
// ln2 (in-place over m1): m1 = tanh(LN(m1 + relu(P0+P1+bm))*g+b)
// P = h2 partials [2][1024][1024]
// ---------------------------------------------------------------------------
__global__ __launch_bounds__(256)
void ln2_kern(float* m1io, const float* __restrict__ P,
              const float* __restrict__ bm,
              const float* __restrict__ g, const float* __restrict__ bb)
{
    const int row = blockIdx.x;
    const int d   = threadIdx.x << 2;
    const long o  = (long)row * DMEM + d;

    float4 a  = *(const float4*)(m1io + o);
    float4 p0 = *(const float4*)(P + o);
    float4 p1 = *(const float4*)(P + 1048576 + o);
    float4 bv = *(const float4*)&bm[d];
    float h0 = fmaxf(p0.x + p1.x + bv.x, 0.f);
    float h1 = fmaxf(p0.y + p1.y + bv.y, 0.f);
    float h2 = fmaxf(p0.z + p1.z + bv.z, 0.f);
    float h3 = fmaxf(p0.w + p1.w + bv.w, 0.f);
    float x0 = a.x + h0, x1 = a.y + h1, x2 = a.z + h2, x3 = a.w + h3;

    float s1 = x0 + x1 + x2 + x3;
    float s2 = x0 * x0 + x1 * x1 + x2 * x2 + x3 * x3;
    block_reduce2(s1, s2);
    float mean = s1 * (1.f / 1024.f);
    float var  = s2 * (1.f / 1024.f) - mean * mean;
    float inv  = 1.f / sqrtf(var + 1e-5f);

    float4 gg = *(const float4*)&g[d];
    float4 b2 = *(const float4*)&bb[d];
    *(float4*)(m1io + o) =
        make_float4(tanhf((x0 - mean) * inv * gg.x + b2.x),
                    tanhf((x1 - mean) * inv * gg.y + b2.y),
                    tanhf((x2 - mean) * inv * gg.z + b2.z),
                    tanhf((x3 - mean) * inv * gg.w + b2.w));
}

// ---------------------------------------------------------------------------
// gate + fused next-step ln1:
//   out = sigmoid(gm+gi+ib)*t2 + sigmoid(gm'+gi'+fb)*mem
//   if !last: m1 = LN(out + v[:,t+1])*g+b ; tm = tanh(out)
// (t2 and m1 may alias: reads complete before writes via block_reduce2 barrier)
// ---------------------------------------------------------------------------
__global__ __launch_bounds__(256)
void gate_ln1_kern(const float* __restrict__ gm, const float* __restrict__ gi,
                   int t, const float* t2, const float* __restrict__ memprev,
                   const float* __restrict__ fbp, const float* __restrict__ ibp,
                   const float* __restrict__ v,
                   const float* __restrict__ g, const float* __restrict__ bb,
                   float* __restrict__ outp, float* m1, float* __restrict__ tm,
                   int last)
{
    const int row = blockIdx.x;          // b*8+s
    const int b   = row >> 3;
    const int d   = threadIdx.x << 2;
    const float ib = *ibp;
    const float fb = *fbp;

    float4 g0 = *(const float4*)(gm + (long)row * NGATES + d);
    float4 g1 = *(const float4*)(gm + (long)row * NGATES + DMEM + d);
    float4 i0 = *(const float4*)(gi + ((long)b * NT + t) * NGATES + d);
    float4 i1 = *(const float4*)(gi + ((long)b * NT + t) * NGATES + DMEM + d);
    float4 tv = *(const float4*)(t2 + (long)row * DMEM + d);
    float4 mv = *(const float4*)(memprev + (long)row * DMEM + d);

    float4 o;
    o.x = sigm(g0.x + i0.x + ib) * tv.x + sigm(g1.x + i1.x + fb) * mv.x;
    o.y = sigm(g0.y + i0.y + ib) * tv.y + sigm(g1.y + i1.y + fb) * mv.y;
    o.z = sigm(g0.z + i0.z + ib) * tv.z + sigm(g1.z + i1.z + fb) * mv.z;
    o.w = sigm(g0.w + i0.w + ib) * tv.w + sigm(g1.w + i1.w + fb) * mv.w;
    *(float4*)(outp + (long)row * DMEM + d) = o;

    if (!last) {
        float4 vv = *(const float4*)(v + ((long)b * NT + t + 1) * DMEM + d);
        *(float4*)(tm + (long)row * DMEM + d) =
            make_float4(tanhf(o.x), tanhf(o.y), tanhf(o.z), tanhf(o.w));

        float x0 = o.x + vv.x, x1 = o.y + vv.y, x2 = o.z + vv.z, x3 = o.w + vv.w;
        float s1 = x0 + x1 + x2 + x3;
        float s2 = x0 * x0 + x1 * x1 + x2 * x2 + x3 * x3;
        block_reduce2(s1, s2);
        float mean = s1 * (1.f / 1024.f);
        float var  = s2 * (1.f / 1024.f) - mean * mean;
        float inv  = 1.f / sqrtf(var + 1e-5f);

        float4 gg = *(const float4*)&g[d];
        float4 bv = *(const float4*)&bb[d];
        *(float4*)(m1 + (long)row * DMEM + d) =
            make_float4((x0 - mean) * inv * gg.x + bv.x,
                        (x1 - mean) * inv * gg.y + bv.y,
                        (x2 - mean) * inv * gg.z + bv.z,
                        (x3 - mean) * inv * gg.w + bv.w);
    }
}

// ---------------------------------------------------------------------------
// ga (in-place): inp = relu(rep_w * inp)
// ---------------------------------------------------------------------------
__global__ __launch_bounds__(256)
void ga_kern(float* __restrict__ inp, const float* __restrict__ rep)
{
    long i4 = ((long)blockIdx.x * 256 + threadIdx.x) << 2;
    float4 x = *(const float4*)&inp[i4];
    float4 r = *(const float4*)&rep[i4 & (DMEM - 1)];
    *(float4*)&inp[i4] = make_float4(fmaxf(r.x * x.x, 0.f), fmaxf(r.y * x.y, 0.f),
                                     fmaxf(r.z * x.z, 0.f), fmaxf(r.w * x.w, 0.f));
}

// ---------------------------------------------------------------------------
extern "C" void kernel_launch(void* const* d_in, const int* in_sizes, int n_in,
                              void* d_out, int out_size, void* d_ws, size_t ws_size,
                              hipStream_t stream)
{
    const float* x    = (const float*)d_in[0];
    const float* mem0 = (const float*)d_in[1];
    const float* Wi   = (const float*)d_in[2];
    const float* bi   = (const float*)d_in[3];
    // d_in[4..7] = Wq,bq,Wk,bk : dead (softmax over singleton axis == 1)
    const float* Wv   = (const float*)d_in[8];
    const float* bv   = (const float*)d_in[9];
    const float* Wm   = (const float*)d_in[10];
    const float* bm   = (const float*)d_in[11];
    const float* ln1g = (const float*)d_in[12];
    const float* ln1b = (const float*)d_in[13];
    const float* ln2g = (const float*)d_in[14];
    const float* ln2b = (const float*)d_in[15];
    const float* repw = (const float*)d_in[16];
    const float* Wg   = (const float*)d_in[17];
    const float* bg   = (const float*)d_in[18];
    const float* Wmg  = (const float*)d_in[19];
    const float* fbp  = (const float*)d_in[20];
    const float* ibp  = (const float*)d_in[21];

    float* out = (float*)d_out;
    char*  ws  = (char*)d_ws;
    const long MB = 1024L * 1024L;

    // persistent across scan
    float* v    = (float*)(ws + 0 * MB);   // 16 MB [4096][1024]
    float* gi   = (float*)(ws + 16 * MB);  // 32 MB [4096][2048]
    // per-step (overlay phase-A transient `inp` @48..64)
    float* m1   = (float*)(ws + 48 * MB);  //  4 MB [1024][1024]  (doubles as t2)
    float* tm   = (float*)(ws + 52 * MB);  //  4 MB
    float* hP   = (float*)(ws + 56 * MB);  //  8 MB [2][1024][1024] h1 partials
    float* gm   = (float*)(ws + 64 * MB);  //  8 MB [1024][2048]
    float* h2P  = (float*)(ws + 72 * MB);  //  8 MB [2][1024][1024] h2 partials
    // phase-A transient
    float* inp  = (float*)(ws + 48 * MB);  // 16 MB [4096][1024]
    // peak: 80 MB (same as round-1)

    dim3 blk(256);

    // ---- phase A ----
    // inp = x @ Wi + bi
    gemm128<<<dim3(8, 32, 1), blk, 0, stream>>>(x, 1024, Wi, 1024, bi, inp, 1024);
    // v = inp @ Wv + bv
    gemm128<<<dim3(8, 32, 1), blk, 0, stream>>>(inp, 1024, Wv, 1024, bv, v, 1024);
    // inp <- relu(rep_w * inp)
    ga_kern<<<4096, blk, 0, stream>>>(inp, repw);
    // gi = ga @ Wg + bg
    gemm128<<<dim3(16, 32, 1), blk, 0, stream>>>(inp, 1024, Wg, 2048, bg, gi, 1024);

    // ---- t=0 LN1 + tanh(mem0) ----
    ln1_kern<<<1024, blk, 0, stream>>>(mem0, v, ln1g, ln1b, m1, tm);

    // ---- recurrent scan; state lives in d_out (outs[t] == new_mem_t) ----
    const long stepN = (long)NB * 8 * DMEM;   // 1,048,576 floats
    for (int t = 0; t < NT; ++t) {
        const float* memprev = (t == 0) ? mem0 : out + (long)(t - 1) * stepN;

        // gm[b,s,:] = tm[b,s,:] @ Wmg[s]  (batched over slots)
        gemm64<0, 2><<<dim3(32, 2, 8), blk, 0, stream>>>(
            tm, 8192, 1024, 0, nullptr, Wmg, 2048, 2097152, gm, 16384, 2048, 1024);
        // h1 partials = m1 @ Wm   (split-K 2)
        gemm64<0, 1><<<dim3(16, 16, 2), blk, 0, stream>>>(
            m1, 1024, 0, 0, nullptr, Wm, 1024, 0, hP, 1024, 1048576, 1024);
        // h2 partials = relu(hP0+hP1+bm) @ Wm   (split-K 2)
        gemm64<1, 1><<<dim3(16, 16, 2), blk, 0, stream>>>(
            hP, 1024, 0, 1048576, bm, Wm, 1024, 0, h2P, 1024, 1048576, 1024);
        // m1 <- tanh(LN(m1 + relu(h2P0+h2P1+bm)))
        ln2_kern<<<1024, blk, 0, stream>>>(m1, h2P, bm, ln2g, ln2b);
        // gates + state update + fused next-step LN1/tanh
        gate_ln1_kern<<<1024, blk, 0, stream>>>(
            gm, gi, t, m1, memprev, fbp, ibp, v, ln1g, ln1b,
            out + (long)t * stepN, m1, tm, (t == NT - 1) ? 1 : 0);
    }

    // final_mem = outs[31]
    hipMemcpyAsync(out + 32L * stepN, out + 31L * stepN, stepN * sizeof(float),
                   hipMemcpyDeviceToDevice, stream);
}